// Round 6
// baseline (483.429 us; speedup 1.0000x reference)
//
#include <hip/hip_runtime.h>
#include <math.h>

#define NNODES 50000
#define NEDGES 800000
#define NGRAPH 64
#define DIM_IN 128
#define HCDIM  192
#define QKVRW  768

typedef __attribute__((ext_vector_type(8))) short short8;
typedef __attribute__((ext_vector_type(4))) float f32x4;
typedef __attribute__((ext_vector_type(2))) float f32x2;

__device__ __forceinline__ unsigned short f2bf(float f){
  unsigned int u = __float_as_uint(f);
  unsigned int r = (u + 0x7fffu + ((u>>16)&1u)) >> 16;
  return (unsigned short)r;
}

__device__ __forceinline__ float4 bf4_to_f4(uint2 u){
  float4 f;
  f.x = __uint_as_float(u.x<<16);
  f.y = __uint_as_float(u.x & 0xffff0000u);
  f.z = __uint_as_float(u.y<<16);
  f.w = __uint_as_float(u.y & 0xffff0000u);
  return f;
}

__device__ __forceinline__ float4 fp8x4_to_f4(unsigned int u){
  f32x2 lo = __builtin_amdgcn_cvt_pk_f32_fp8((int)u, false);
  f32x2 hi = __builtin_amdgcn_cvt_pk_f32_fp8((int)u, true);
  float4 f; f.x=lo[0]; f.y=lo[1]; f.z=hi[0]; f.w=hi[1];
  return f;
}

__device__ __forceinline__ float wave_sum(float v){
#pragma unroll
  for(int off=32; off>0; off>>=1) v += __shfl_xor(v, off, 64);
  return v;
}

// ---------------- CSR build ----------------
__global__ void zero_i(int* p, int n){
  int i = blockIdx.x*blockDim.x + threadIdx.x;
  if(i<n) p[i]=0;
}

__global__ void zero2_k(int* a, int* b, int n){
  int i = blockIdx.x*blockDim.x + threadIdx.x;
  if(i<n){ a[i]=0; b[i]=0; }
}

__global__ void hist_k(const int* __restrict__ dst, int* __restrict__ counts, int E){
  int e = blockIdx.x*blockDim.x + threadIdx.x;
  if(e<E) atomicAdd(&counts[dst[e]], 1);
}

__global__ void scan_partial(const int* __restrict__ counts, int* __restrict__ bsum, int N){
  __shared__ int lds[256];
  int t = threadIdx.x;
  int idx = blockIdx.x*256 + t;
  int v = (idx<N)? counts[idx] : 0;
  lds[t]=v; __syncthreads();
#pragma unroll
  for(int off=128; off>0; off>>=1){
    if(t<off) lds[t]+=lds[t+off];
    __syncthreads();
  }
  if(t==0) bsum[blockIdx.x]=lds[0];
}

__global__ void scan_bsum(int* bsum, int nb){
  __shared__ int lds[1024];
  int t=threadIdx.x;
  int v=(t<nb)?bsum[t]:0;
  lds[t]=v; __syncthreads();
  int x=v;
#pragma unroll
  for(int off=1; off<1024; off<<=1){
    int y=(t>=off)?lds[t-off]:0;
    __syncthreads();
    x+=y; lds[t]=x;
    __syncthreads();
  }
  if(t<nb) bsum[t]=x-v;
}

__global__ void scan_final(const int* __restrict__ counts, const int* __restrict__ bsum,
                           int* __restrict__ row_ptr, int N){
  __shared__ int lds[256];
  int t=threadIdx.x;
  int idx=blockIdx.x*256+t;
  int v=(idx<N)?counts[idx]:0;
  lds[t]=v; __syncthreads();
  int x=v;
#pragma unroll
  for(int off=1; off<256; off<<=1){
    int y=(t>=off)?lds[t-off]:0;
    __syncthreads();
    x+=y; lds[t]=x;
    __syncthreads();
  }
  if(idx<=N) row_ptr[idx]= bsum[blockIdx.x]+x-v;
}

__global__ void fill_k(const int* __restrict__ src, const int* __restrict__ dst,
                       const int* __restrict__ row_ptr, int* __restrict__ cursor,
                       int* __restrict__ csr_src, int E){
  int e = blockIdx.x*blockDim.x + threadIdx.x;
  if(e<E){
    int d = dst[e];
    int pos = row_ptr[d] + atomicAdd(&cursor[d], 1);
    csr_src[pos] = src[e];
  }
}

// ---------------- weight prep ----------------
__global__ void cast_bf16(const float* __restrict__ X, unsigned short* __restrict__ Xb, int n4){
  int i = blockIdx.x*blockDim.x + threadIdx.x;
  int i4 = i*4;
  if(i4 < n4){
    float4 v = *(const float4*)(X+i4);
    ushort4 o; o.x=f2bf(v.x); o.y=f2bf(v.y); o.z=f2bf(v.z); o.w=f2bf(v.w);
    *(ushort4*)(Xb+i4) = o;
  }
}

__global__ void build_wt(const float* __restrict__ Wq, const float* __restrict__ Wk,
                         const float* __restrict__ Wv, const float* __restrict__ Ws,
                         const float* __restrict__ bq, const float* __restrict__ bk,
                         const float* __restrict__ bv, const float* __restrict__ bs,
                         unsigned short* __restrict__ Wt, float* __restrict__ bcat, int K){
  int idx = blockIdx.x*256 + threadIdx.x;
  if(idx < QKVRW*K){
    int c = idx / K, k = idx % K;
    int mat = c/HCDIM, cm = c%HCDIM;
    const float* W = (mat==0)?Wq:(mat==1)?Wk:(mat==2)?Wv:Ws;
    Wt[(size_t)c*K + k] = f2bf(W[(size_t)k*HCDIM + cm]);
  }
  if(idx < QKVRW){
    int mat = idx/HCDIM, cm = idx%HCDIM;
    const float* b = (mat==0)?bq:(mat==1)?bk:(mat==2)?bv:bs;
    bcat[idx] = b[cm];
  }
}

// ---------------- bf16 MFMA projection GEMM (BK=64 K-loop) ----------------
// cols 0-191 -> Q (bf16); 192-383 -> K (fp8); 384-575 -> V (fp8); 576-767 -> R (bf16)
template<int K>
__global__ __launch_bounds__(256) void gemm_mfma(
    const unsigned short* __restrict__ Xb,
    const unsigned short* __restrict__ Wt,
    const float* __restrict__ bcat,
    unsigned short* __restrict__ QR,
    unsigned char* __restrict__ KV, int N)
{
  __shared__ unsigned short As[128*64];
  __shared__ unsigned short Bs[64*64];
  const int tid = threadIdx.x;
  const int wv = tid>>6;
  const int lane = tid&63;
  const int m0  = blockIdx.x*128;
  const int cb  = blockIdx.y;           // 0..11
  const int mat = cb/3;
  const int nc0 = cb*64;                // global col

  const int wr = wv>>1, wc = wv&1;      // wave tile 64(M) x 32(N)
  const int lhi = lane>>4, llo = lane&15;
  f32x4 acc[4][2] = {};

  constexpr int NT = K/64;
#pragma unroll
  for(int kt=0; kt<NT; ++kt){
    if(kt>0) __syncthreads();
    // stage A: 128 rows x 64 ch (8 chunks/row), XOR-swizzled source
#pragma unroll
    for(int it=0; it<4; ++it){
      int p = it*256 + tid;
      int r = p>>3, c = p&7;
      int cs = c ^ (r&7);
      int grow = m0 + r; if(grow > N-1) grow = N-1;
      const unsigned short* gp = Xb + (size_t)grow*K + kt*64 + cs*8;
      unsigned short* lp = As + (size_t)(it*256 + wv*64)*8;
      __builtin_amdgcn_global_load_lds(
          (const __attribute__((address_space(1))) unsigned int*)gp,
          (__attribute__((address_space(3))) unsigned int*)lp, 16, 0, 0);
    }
    // stage B: 64 rows x 64 ch
#pragma unroll
    for(int it=0; it<2; ++it){
      int p = it*256 + tid;
      int r = p>>3, c = p&7;
      int cs = c ^ (r&7);
      const unsigned short* gp = Wt + (size_t)(nc0 + r)*K + kt*64 + cs*8;
      unsigned short* lp = Bs + (size_t)(it*256 + wv*64)*8;
      __builtin_amdgcn_global_load_lds(
          (const __attribute__((address_space(1))) unsigned int*)gp,
          (__attribute__((address_space(3))) unsigned int*)lp, 16, 0, 0);
    }
    __syncthreads();

#pragma unroll
    for(int kk=0; kk<64; kk+=32){
      short8 a[4], b[2];
      const int chunk = (kk>>3) + lhi;
#pragma unroll
      for(int i=0;i<4;++i){
        int rr = wr*64 + i*16 + llo;
        int cs = chunk ^ (rr&7);
        a[i] = *(const short8*)(As + rr*64 + cs*8);
      }
#pragma unroll
      for(int j=0;j<2;++j){
        int cc = wc*32 + j*16 + llo;
        int cs = chunk ^ (cc&7);
        b[j] = *(const short8*)(Bs + cc*64 + cs*8);
      }
#pragma unroll
      for(int i=0;i<4;++i)
#pragma unroll
        for(int j=0;j<2;++j)
          acc[i][j] = __builtin_amdgcn_mfma_f32_16x16x32_bf16(a[i], b[j], acc[i][j], 0,0,0);
    }
  }

  const int col0 = nc0 + wc*32 + llo;
  float bias0 = bcat[col0];
  float bias1 = bcat[col0+16];
  if(mat==0 || mat==3){
    const int coff = (mat==0) ? col0 : col0-384;   // QR halves: Q at 0.., R at 192..
#pragma unroll
    for(int i=0;i<4;++i){
#pragma unroll
      for(int r=0;r<4;++r){
        int grow = m0 + wr*64 + i*16 + lhi*4 + r;
        if(grow < N){
          size_t base = (size_t)grow*384 + coff;
          QR[base]      = f2bf(acc[i][0][r] + bias0);
          QR[base + 16] = f2bf(acc[i][1][r] + bias1);
        }
      }
    }
  } else {
    // fp8 pack: even lane pairs (cols col0, col0+1)
#pragma unroll
    for(int i=0;i<4;++i){
#pragma unroll
      for(int r=0;r<4;++r){
        int grow = m0 + wr*64 + i*16 + lhi*4 + r;
        float v0 = acc[i][0][r] + bias0;
        float v1 = acc[i][1][r] + bias1;
        float n0 = __shfl_xor(v0, 1, 64);
        float n1 = __shfl_xor(v1, 1, 64);
        if(((llo&1)==0) && grow < N){
          int p0 = __builtin_amdgcn_cvt_pk_fp8_f32(v0, n0, 0, false);
          int p1 = __builtin_amdgcn_cvt_pk_fp8_f32(v1, n1, 0, false);
          unsigned char* kb = KV + (size_t)grow*384 + (col0-192);
          *(unsigned short*)(kb)    = (unsigned short)(p0 & 0xffff);
          *(unsigned short*)(kb+16) = (unsigned short)(p1 & 0xffff);
        }
      }
    }
  }
}

// ---------------- single-pass attention + gated skip + ELU ----------------
// Q,R bf16 in QR[N][384]; K,V fp8 in KV[N][384]
// 1 wave = 1 node; 8 edges in flight, 8 lanes per edge (lane octet = 8 channels/head)
template<bool OUTBF>
__global__ __launch_bounds__(256) void attn_kernel(
  const unsigned short* __restrict__ QR,
  const unsigned char* __restrict__ KV,
  const int* __restrict__ row_ptr, const int* __restrict__ csr_src,
  const float* __restrict__ Wb, float* __restrict__ HoutF,
  unsigned short* __restrict__ HoutB, int N)
{
  const int wave = threadIdx.x>>6;
  const int lane = threadIdx.x&63;
  const int g    = lane>>3;          // edge slot 0..7
  const int j    = lane&7;           // channel octet 0..7
  const int n = blockIdx.x*4 + wave;
  if(n>=N) return;

  // Q: 8 channels per head per lane
  float4 qL[3], qH[3];
#pragma unroll
  for(int h=0;h<3;++h){
    uint4 uu = *(const uint4*)(QR + (size_t)n*384 + h*64 + j*8);
    qL[h] = bf4_to_f4(make_uint2(uu.x,uu.y));
    qH[h] = bf4_to_f4(make_uint2(uu.z,uu.w));
  }

  const int s0 = row_ptr[n];
  const int deg = row_ptr[n+1]-s0;

  float4 aL[3]={{0,0,0,0},{0,0,0,0},{0,0,0,0}};
  float4 aH[3]={{0,0,0,0},{0,0,0,0},{0,0,0,0}};
  float dsum[3]={0,0,0};

  int sCur = csr_src[s0 + (g<deg ? g : 0)];
  for(int base=0; base<deg; base+=8){
    const int inext = base + 8 + g;
    const int sNxt = csr_src[s0 + (inext<deg ? inext : 0)];
    const bool valid = (base + g < deg);
    const unsigned int* kv = (const unsigned int*)(KV + (size_t)sCur*384);
    float p[3];
#pragma unroll
    for(int h=0;h<3;++h){
      unsigned int k0 = kv[h*16 + j*2];
      unsigned int k1 = kv[h*16 + j*2 + 1];
      float4 kA = fp8x4_to_f4(k0);
      float4 kB = fp8x4_to_f4(k1);
      p[h] = qL[h].x*kA.x + qL[h].y*kA.y + qL[h].z*kA.z + qL[h].w*kA.w
           + qH[h].x*kB.x + qH[h].y*kB.y + qH[h].z*kB.z + qH[h].w*kB.w;
    }
#pragma unroll
    for(int off=1; off<8; off<<=1){
      p[0] += __shfl_xor(p[0], off, 64);
      p[1] += __shfl_xor(p[1], off, 64);
      p[2] += __shfl_xor(p[2], off, 64);
    }
    float e0 = valid ? __expf(0.125f*p[0]) : 0.f;
    float e1 = valid ? __expf(0.125f*p[1]) : 0.f;
    float e2 = valid ? __expf(0.125f*p[2]) : 0.f;
    dsum[0]+=e0; dsum[1]+=e1; dsum[2]+=e2;
    float ee[3] = {e0,e1,e2};
#pragma unroll
    for(int h=0;h<3;++h){
      unsigned int v0 = kv[48 + h*16 + j*2];
      unsigned int v1 = kv[48 + h*16 + j*2 + 1];
      float4 vA = fp8x4_to_f4(v0);
      float4 vB = fp8x4_to_f4(v1);
      aL[h].x+=ee[h]*vA.x; aL[h].y+=ee[h]*vA.y; aL[h].z+=ee[h]*vA.z; aL[h].w+=ee[h]*vA.w;
      aH[h].x+=ee[h]*vB.x; aH[h].y+=ee[h]*vB.y; aH[h].z+=ee[h]*vB.z; aH[h].w+=ee[h]*vB.w;
    }
    sCur = sNxt;
  }

  // cross-group reduction (edge slots hold disjoint subsets)
#pragma unroll
  for(int off=8; off<64; off<<=1){
#pragma unroll
    for(int h=0;h<3;++h){
      aL[h].x+=__shfl_xor(aL[h].x,off,64); aL[h].y+=__shfl_xor(aL[h].y,off,64);
      aL[h].z+=__shfl_xor(aL[h].z,off,64); aL[h].w+=__shfl_xor(aL[h].w,off,64);
      aH[h].x+=__shfl_xor(aH[h].x,off,64); aH[h].y+=__shfl_xor(aH[h].y,off,64);
      aH[h].z+=__shfl_xor(aH[h].z,off,64); aH[h].w+=__shfl_xor(aH[h].w,off,64);
      dsum[h]+=__shfl_xor(dsum[h],off,64);
    }
  }

  float4 oL[3], oH[3], rL[3], rH[3];
#pragma unroll
  for(int h=0;h<3;++h){
    float id = 1.f/(dsum[h]+1e-16f);
    oL[h].x=aL[h].x*id; oL[h].y=aL[h].y*id; oL[h].z=aL[h].z*id; oL[h].w=aL[h].w*id;
    oH[h].x=aH[h].x*id; oH[h].y=aH[h].y*id; oH[h].z=aH[h].z*id; oH[h].w=aH[h].w*id;
    uint4 uu = *(const uint4*)(QR + (size_t)n*384 + 192 + h*64 + j*8);
    rL[h] = bf4_to_f4(make_uint2(uu.x,uu.y));
    rH[h] = bf4_to_f4(make_uint2(uu.z,uu.w));
  }

  float z = 0.f;
#pragma unroll
  for(int h=0;h<3;++h){
    const int c = h*64 + j*8;
    float4 woL=*(const float4*)(Wb+c),     woH=*(const float4*)(Wb+c+4);
    float4 wrL=*(const float4*)(Wb+192+c), wrH=*(const float4*)(Wb+192+c+4);
    float4 wdL=*(const float4*)(Wb+384+c), wdH=*(const float4*)(Wb+384+c+4);
    z += oL[h].x*woL.x+oL[h].y*woL.y+oL[h].z*woL.z+oL[h].w*woL.w
       + oH[h].x*woH.x+oH[h].y*woH.y+oH[h].z*woH.z+oH[h].w*woH.w
       + rL[h].x*wrL.x+rL[h].y*wrL.y+rL[h].z*wrL.z+rL[h].w*wrL.w
       + rH[h].x*wrH.x+rH[h].y*wrH.y+rH[h].z*wrH.z+rH[h].w*wrH.w
       + (oL[h].x-rL[h].x)*wdL.x+(oL[h].y-rL[h].y)*wdL.y
       + (oL[h].z-rL[h].z)*wdL.z+(oL[h].w-rL[h].w)*wdL.w
       + (oH[h].x-rH[h].x)*wdH.x+(oH[h].y-rH[h].y)*wdH.y
       + (oH[h].z-rH[h].z)*wdH.z+(oH[h].w-rH[h].w)*wdH.w;
  }
#pragma unroll
  for(int off=1; off<8; off<<=1) z += __shfl_xor(z, off, 64);
  const float beta = 1.f/(1.f+__expf(-z));

  if(g==0){
#pragma unroll
    for(int h=0;h<3;++h){
      float4 hL, hH;
      hL.x=beta*rL[h].x+(1.f-beta)*oL[h].x; hL.y=beta*rL[h].y+(1.f-beta)*oL[h].y;
      hL.z=beta*rL[h].z+(1.f-beta)*oL[h].z; hL.w=beta*rL[h].w+(1.f-beta)*oL[h].w;
      hH.x=beta*rH[h].x+(1.f-beta)*oH[h].x; hH.y=beta*rH[h].y+(1.f-beta)*oH[h].y;
      hH.z=beta*rH[h].z+(1.f-beta)*oH[h].z; hH.w=beta*rH[h].w+(1.f-beta)*oH[h].w;
      hL.x=(hL.x>0.f)?hL.x:expm1f(hL.x); hL.y=(hL.y>0.f)?hL.y:expm1f(hL.y);
      hL.z=(hL.z>0.f)?hL.z:expm1f(hL.z); hL.w=(hL.w>0.f)?hL.w:expm1f(hL.w);
      hH.x=(hH.x>0.f)?hH.x:expm1f(hH.x); hH.y=(hH.y>0.f)?hH.y:expm1f(hH.y);
      hH.z=(hH.z>0.f)?hH.z:expm1f(hH.z); hH.w=(hH.w>0.f)?hH.w:expm1f(hH.w);
      if(OUTBF){
        unsigned short* hb = HoutB + (size_t)n*HCDIM + h*64 + j*8;
        ushort4 uL, uH;
        uL.x=f2bf(hL.x); uL.y=f2bf(hL.y); uL.z=f2bf(hL.z); uL.w=f2bf(hL.w);
        uH.x=f2bf(hH.x); uH.y=f2bf(hH.y); uH.z=f2bf(hH.z); uH.w=f2bf(hH.w);
        *(ushort4*)(hb)   = uL;
        *(ushort4*)(hb+4) = uH;
      } else {
        float* ho = HoutF + (size_t)n*HCDIM + h*64 + j*8;
        *(float4*)(ho)   = hL;
        *(float4*)(ho+4) = hH;
      }
    }
  }
}

// ---------------- pooling + logits ----------------
__global__ void zero_pool(float* pooled, int* cnt){
  int i = blockIdx.x*256 + threadIdx.x;
  if(i < NGRAPH*HCDIM) ((int*)pooled)[i]=0;
  if(i < NGRAPH) cnt[i]=0;
}

__global__ void cnt_k(const int* __restrict__ batch, int* __restrict__ cnt, int N){
  __shared__ int h[NGRAPH];
  const int t = threadIdx.x;
  if(t<NGRAPH) h[t]=0;
  __syncthreads();
  int i = blockIdx.x*blockDim.x + t;
  if(i<N) atomicAdd(&h[batch[i]], 1);
  __syncthreads();
  if(t<NGRAPH && h[t]) atomicAdd(&cnt[t], h[t]);
}

__global__ void pool_k(const float* __restrict__ H, const int* __restrict__ batch,
                       float* __restrict__ pooled, int N){
  const int t = threadIdx.x;       // 192 threads = channel
  int start = blockIdx.x*256;
  int end = min(start+256, N);
  if(start>=N) return;
  int cur = batch[start];
  float acc = 0.f;
  for(int nn=start; nn<end; ++nn){
    int g = batch[nn];
    if(g!=cur){ atomicAdd(&pooled[(size_t)cur*HCDIM+t], acc); acc=0.f; cur=g; }
    acc += H[(size_t)nn*HCDIM+t];
  }
  atomicAdd(&pooled[(size_t)cur*HCDIM+t], acc);
}

__global__ void logits_k(const float* __restrict__ pooled, const int* __restrict__ cnt,
                         const float* __restrict__ Wlin, const float* __restrict__ blin,
                         float* __restrict__ out){
  const int g = blockIdx.x;
  const int lane = threadIdx.x;    // 64 threads
  float c = fmaxf((float)cnt[g], 1.f);
  float s = 0.f;
#pragma unroll
  for(int j=0;j<3;++j){
    int col = j*64+lane;
    s += pooled[(size_t)g*HCDIM+col]/c * Wlin[col];
  }
  s = wave_sum(s);
  if(lane==0) out[g] = s + blin[0];
}

extern "C" void kernel_launch(void* const* d_in, const int* in_sizes, int n_in,
                              void* d_out, int out_size, void* d_ws, size_t ws_size,
                              hipStream_t stream)
{
  const int N=NNODES, E=NEDGES;
  const float* x     = (const float*)d_in[0];
  const int*   ei    = (const int*)d_in[1];
  const int*   batch = (const int*)d_in[2];
  const int* esrc = ei;
  const int* edst = ei + E;
  const float* Wq0=(const float*)d_in[3];  const float* bq0=(const float*)d_in[4];
  const float* Wk0=(const float*)d_in[5];  const float* bk0=(const float*)d_in[6];
  const float* Wv0=(const float*)d_in[7];  const float* bv0=(const float*)d_in[8];
  const float* Ws0=(const float*)d_in[9];  const float* bs0=(const float*)d_in[10];
  const float* Wb0=(const float*)d_in[11];
  const float* Wq1=(const float*)d_in[12]; const float* bq1=(const float*)d_in[13];
  const float* Wk1=(const float*)d_in[14]; const float* bk1=(const float*)d_in[15];
  const float* Wv1=(const float*)d_in[16]; const float* bv1=(const float*)d_in[17];
  const float* Ws1=(const float*)d_in[18]; const float* bs1=(const float*)d_in[19];
  const float* Wb1=(const float*)d_in[20];
  const float* Wlin=(const float*)d_in[21];
  const float* blin=(const float*)d_in[22];
  float* out = (float*)d_out;

  char* p = (char*)d_ws;
  auto alloc = [&](size_t bytes)->char*{
    char* q = p; p += (bytes+255)/256*256; return q;
  };
  unsigned short* Xb   = (unsigned short*)alloc((size_t)N*HCDIM*2);
  unsigned short* QR   = (unsigned short*)alloc((size_t)N*384*2);
  unsigned char*  KV   = (unsigned char*)alloc((size_t)N*384);
  float* H1            = (float*)alloc((size_t)N*HCDIM*4);
  unsigned short* Wt   = (unsigned short*)alloc((size_t)QKVRW*HCDIM*2);
  float* bcat          = (float*)alloc(QKVRW*4);
  int* counts  = (int*)alloc((size_t)N*4);
  int* cursor  = (int*)alloc((size_t)N*4);
  int* row_ptr = (int*)alloc((size_t)(N+1)*4);
  int* csr     = (int*)alloc((size_t)E*4);
  int* bsum    = (int*)alloc(4096);
  float* pooled= (float*)alloc((size_t)NGRAPH*HCDIM*4);
  int* cnt     = (int*)alloc(256);

  const int NB = (N+255)/256;

  // ---- CSR build ----
  zero2_k<<<(N+255)/256,256,0,stream>>>(counts,cursor,N);
  hist_k<<<(E+255)/256,256,0,stream>>>(edst,counts,E);
  scan_partial<<<NB,256,0,stream>>>(counts,bsum,N);
  scan_bsum<<<1,1024,0,stream>>>(bsum,NB);
  scan_final<<<NB,256,0,stream>>>(counts,bsum,row_ptr,N);
  fill_k<<<(E+255)/256,256,0,stream>>>(esrc,edst,row_ptr,cursor,csr,E);

  dim3 ggemm((N+127)/128, 12);
  // ---- layer 0 ----
  cast_bf16<<<((N*DIM_IN/4)+255)/256,256,0,stream>>>(x, Xb, N*DIM_IN);
  build_wt<<<(QKVRW*DIM_IN+255)/256,256,0,stream>>>(Wq0,Wk0,Wv0,Ws0,bq0,bk0,bv0,bs0,Wt,bcat,DIM_IN);
  gemm_mfma<DIM_IN><<<ggemm,256,0,stream>>>(Xb,Wt,bcat,QR,KV,N);
  attn_kernel<true><<<(N+3)/4,256,0,stream>>>(QR,KV,row_ptr,csr,Wb0,nullptr,Xb,N);
  // ---- layer 1 ----
  build_wt<<<(QKVRW*HCDIM+255)/256,256,0,stream>>>(Wq1,Wk1,Wv1,Ws1,bq1,bk1,bv1,bs1,Wt,bcat,HCDIM);
  gemm_mfma<HCDIM><<<ggemm,256,0,stream>>>(Xb,Wt,bcat,QR,KV,N);
  attn_kernel<false><<<(N+3)/4,256,0,stream>>>(QR,KV,row_ptr,csr,Wb1,H1,nullptr,N);

  // ---- pooling + logits ----
  zero_pool<<<(NGRAPH*HCDIM+255)/256,256,0,stream>>>(pooled,cnt);
  cnt_k<<<(N+255)/256,256,0,stream>>>(batch,cnt,N);
  pool_k<<<(N+255)/256,192,0,stream>>>(H1,batch,pooled,N);
  logits_k<<<NGRAPH,64,0,stream>>>(pooled,cnt,Wlin,blin,out);
}

// Round 7
// 406.108 us; speedup vs baseline: 1.1904x; 1.1904x over previous
//
#include <hip/hip_runtime.h>
#include <math.h>

#define NNODES 50000
#define NEDGES 800000
#define NGRAPH 64
#define DIM_IN 128
#define HCDIM  192
#define QKVRW  768

typedef __attribute__((ext_vector_type(8))) short short8;
typedef __attribute__((ext_vector_type(4))) float f32x4;
typedef __attribute__((ext_vector_type(2))) float f32x2;

__device__ __forceinline__ unsigned short f2bf(float f){
  unsigned int u = __float_as_uint(f);
  unsigned int r = (u + 0x7fffu + ((u>>16)&1u)) >> 16;
  return (unsigned short)r;
}

__device__ __forceinline__ float4 bf4_to_f4(uint2 u){
  float4 f;
  f.x = __uint_as_float(u.x<<16);
  f.y = __uint_as_float(u.x & 0xffff0000u);
  f.z = __uint_as_float(u.y<<16);
  f.w = __uint_as_float(u.y & 0xffff0000u);
  return f;
}

__device__ __forceinline__ float4 fp8x4_to_f4(unsigned int u){
  f32x2 lo = __builtin_amdgcn_cvt_pk_f32_fp8((int)u, false);
  f32x2 hi = __builtin_amdgcn_cvt_pk_f32_fp8((int)u, true);
  float4 f; f.x=lo[0]; f.y=lo[1]; f.z=hi[0]; f.w=hi[1];
  return f;
}

__device__ __forceinline__ float wave_sum(float v){
#pragma unroll
  for(int off=32; off>0; off>>=1) v += __shfl_xor(v, off, 64);
  return v;
}

// ---------------- CSR build ----------------
__global__ void zero2_k(int* a, int* b, int n){
  int i = blockIdx.x*blockDim.x + threadIdx.x;
  if(i<n){ a[i]=0; b[i]=0; }
}

__global__ void hist_k(const int* __restrict__ dst, int* __restrict__ counts, int E){
  int e = blockIdx.x*blockDim.x + threadIdx.x;
  if(e<E) atomicAdd(&counts[dst[e]], 1);
}

__global__ void scan_partial(const int* __restrict__ counts, int* __restrict__ bsum, int N){
  __shared__ int lds[256];
  int t = threadIdx.x;
  int idx = blockIdx.x*256 + t;
  int v = (idx<N)? counts[idx] : 0;
  lds[t]=v; __syncthreads();
#pragma unroll
  for(int off=128; off>0; off>>=1){
    if(t<off) lds[t]+=lds[t+off];
    __syncthreads();
  }
  if(t==0) bsum[blockIdx.x]=lds[0];
}

__global__ void scan_bsum(int* bsum, int nb){
  __shared__ int lds[1024];
  int t=threadIdx.x;
  int v=(t<nb)?bsum[t]:0;
  lds[t]=v; __syncthreads();
  int x=v;
#pragma unroll
  for(int off=1; off<1024; off<<=1){
    int y=(t>=off)?lds[t-off]:0;
    __syncthreads();
    x+=y; lds[t]=x;
    __syncthreads();
  }
  if(t<nb) bsum[t]=x-v;
}

__global__ void scan_final(const int* __restrict__ counts, const int* __restrict__ bsum,
                           int* __restrict__ row_ptr, int N){
  __shared__ int lds[256];
  int t=threadIdx.x;
  int idx=blockIdx.x*256+t;
  int v=(idx<N)?counts[idx]:0;
  lds[t]=v; __syncthreads();
  int x=v;
#pragma unroll
  for(int off=1; off<256; off<<=1){
    int y=(t>=off)?lds[t-off]:0;
    __syncthreads();
    x+=y; lds[t]=x;
    __syncthreads();
  }
  if(idx<=N) row_ptr[idx]= bsum[blockIdx.x]+x-v;
}

__global__ void fill_k(const int* __restrict__ src, const int* __restrict__ dst,
                       const int* __restrict__ row_ptr, int* __restrict__ cursor,
                       int* __restrict__ csr_src, int E){
  int e = blockIdx.x*blockDim.x + threadIdx.x;
  if(e<E){
    int d = dst[e];
    int pos = row_ptr[d] + atomicAdd(&cursor[d], 1);
    csr_src[pos] = src[e];
  }
}

// ---------------- layer-0 prep: cast x to bf16 + build Wt/bcat (fused) ----------------
#define CAST_BLKS (NNODES*DIM_IN/4/256)   // 6250
__global__ void prep0_k(const float* __restrict__ X, unsigned short* __restrict__ Xb,
                        const float* __restrict__ Wq, const float* __restrict__ Wk,
                        const float* __restrict__ Wv, const float* __restrict__ Ws,
                        const float* __restrict__ bq, const float* __restrict__ bk,
                        const float* __restrict__ bv, const float* __restrict__ bs,
                        unsigned short* __restrict__ Wt, float* __restrict__ bcat){
  if(blockIdx.x < CAST_BLKS){
    int i4 = (blockIdx.x*256 + threadIdx.x)*4;
    float4 v = *(const float4*)(X+i4);
    ushort4 o; o.x=f2bf(v.x); o.y=f2bf(v.y); o.z=f2bf(v.z); o.w=f2bf(v.w);
    *(ushort4*)(Xb+i4) = o;
  } else {
    int idx = (blockIdx.x-CAST_BLKS)*256 + threadIdx.x;   // 0..QKVRW*DIM_IN-1
    if(idx < QKVRW*DIM_IN){
      int c = idx / DIM_IN, k = idx % DIM_IN;
      int mat = c/HCDIM, cm = c%HCDIM;
      const float* W = (mat==0)?Wq:(mat==1)?Wk:(mat==2)?Wv:Ws;
      Wt[(size_t)c*DIM_IN + k] = f2bf(W[(size_t)k*HCDIM + cm]);
    }
    if(idx < QKVRW){
      int mat = idx/HCDIM, cm = idx%HCDIM;
      const float* b = (mat==0)?bq:(mat==1)?bk:(mat==2)?bv:bs;
      bcat[idx] = b[cm];
    }
  }
}

__global__ void build_wt(const float* __restrict__ Wq, const float* __restrict__ Wk,
                         const float* __restrict__ Wv, const float* __restrict__ Ws,
                         const float* __restrict__ bq, const float* __restrict__ bk,
                         const float* __restrict__ bv, const float* __restrict__ bs,
                         unsigned short* __restrict__ Wt, float* __restrict__ bcat, int K){
  int idx = blockIdx.x*256 + threadIdx.x;
  if(idx < QKVRW*K){
    int c = idx / K, k = idx % K;
    int mat = c/HCDIM, cm = c%HCDIM;
    const float* W = (mat==0)?Wq:(mat==1)?Wk:(mat==2)?Wv:Ws;
    Wt[(size_t)c*K + k] = f2bf(W[(size_t)k*HCDIM + cm]);
  }
  if(idx < QKVRW){
    int mat = idx/HCDIM, cm = idx%HCDIM;
    const float* b = (mat==0)?bq:(mat==1)?bk:(mat==2)?bv:bs;
    bcat[idx] = b[cm];
  }
}

// ---------------- bf16 MFMA projection GEMM (BK=64 K-loop) ----------------
// cols 0-191 -> Q (bf16); 192-383 -> K (fp8); 384-575 -> V (fp8); 576-767 -> R (bf16)
template<int K>
__global__ __launch_bounds__(256) void gemm_mfma(
    const unsigned short* __restrict__ Xb,
    const unsigned short* __restrict__ Wt,
    const float* __restrict__ bcat,
    unsigned short* __restrict__ QR,
    unsigned char* __restrict__ KV, int N)
{
  __shared__ unsigned short As[128*64];
  __shared__ unsigned short Bs[64*64];
  const int tid = threadIdx.x;
  const int wv = tid>>6;
  const int lane = tid&63;
  const int m0  = blockIdx.x*128;
  const int cb  = blockIdx.y;           // 0..11
  const int mat = cb/3;
  const int nc0 = cb*64;                // global col

  const int wr = wv>>1, wc = wv&1;      // wave tile 64(M) x 32(N)
  const int lhi = lane>>4, llo = lane&15;
  f32x4 acc[4][2] = {};

  constexpr int NT = K/64;
#pragma unroll
  for(int kt=0; kt<NT; ++kt){
    if(kt>0) __syncthreads();
#pragma unroll
    for(int it=0; it<4; ++it){
      int p = it*256 + tid;
      int r = p>>3, c = p&7;
      int cs = c ^ (r&7);
      int grow = m0 + r; if(grow > N-1) grow = N-1;
      const unsigned short* gp = Xb + (size_t)grow*K + kt*64 + cs*8;
      unsigned short* lp = As + (size_t)(it*256 + wv*64)*8;
      __builtin_amdgcn_global_load_lds(
          (const __attribute__((address_space(1))) unsigned int*)gp,
          (__attribute__((address_space(3))) unsigned int*)lp, 16, 0, 0);
    }
#pragma unroll
    for(int it=0; it<2; ++it){
      int p = it*256 + tid;
      int r = p>>3, c = p&7;
      int cs = c ^ (r&7);
      const unsigned short* gp = Wt + (size_t)(nc0 + r)*K + kt*64 + cs*8;
      unsigned short* lp = Bs + (size_t)(it*256 + wv*64)*8;
      __builtin_amdgcn_global_load_lds(
          (const __attribute__((address_space(1))) unsigned int*)gp,
          (__attribute__((address_space(3))) unsigned int*)lp, 16, 0, 0);
    }
    __syncthreads();

#pragma unroll
    for(int kk=0; kk<64; kk+=32){
      short8 a[4], b[2];
      const int chunk = (kk>>3) + lhi;
#pragma unroll
      for(int i=0;i<4;++i){
        int rr = wr*64 + i*16 + llo;
        int cs = chunk ^ (rr&7);
        a[i] = *(const short8*)(As + rr*64 + cs*8);
      }
#pragma unroll
      for(int j=0;j<2;++j){
        int cc = wc*32 + j*16 + llo;
        int cs = chunk ^ (cc&7);
        b[j] = *(const short8*)(Bs + cc*64 + cs*8);
      }
#pragma unroll
      for(int i=0;i<4;++i)
#pragma unroll
        for(int j=0;j<2;++j)
          acc[i][j] = __builtin_amdgcn_mfma_f32_16x16x32_bf16(a[i], b[j], acc[i][j], 0,0,0);
    }
  }

  const int col0 = nc0 + wc*32 + llo;
  float bias0 = bcat[col0];
  float bias1 = bcat[col0+16];
  if(mat==0 || mat==3){
    const int coff = (mat==0) ? col0 : col0-384;   // QR halves: Q at 0.., R at 192..
#pragma unroll
    for(int i=0;i<4;++i){
#pragma unroll
      for(int r=0;r<4;++r){
        int grow = m0 + wr*64 + i*16 + lhi*4 + r;
        if(grow < N){
          size_t base = (size_t)grow*384 + coff;
          QR[base]      = f2bf(acc[i][0][r] + bias0);
          QR[base + 16] = f2bf(acc[i][1][r] + bias1);
        }
      }
    }
  } else {
    // fp8 pack: even lane pairs (cols col0, col0+1)
#pragma unroll
    for(int i=0;i<4;++i){
#pragma unroll
      for(int r=0;r<4;++r){
        int grow = m0 + wr*64 + i*16 + lhi*4 + r;
        float v0 = acc[i][0][r] + bias0;
        float v1 = acc[i][1][r] + bias1;
        float n0 = __shfl_xor(v0, 1, 64);
        float n1 = __shfl_xor(v1, 1, 64);
        if(((llo&1)==0) && grow < N){
          int p0 = __builtin_amdgcn_cvt_pk_fp8_f32(v0, n0, 0, false);
          int p1 = __builtin_amdgcn_cvt_pk_fp8_f32(v1, n1, 0, false);
          unsigned char* kb = KV + (size_t)grow*384 + (col0-192);
          *(unsigned short*)(kb)    = (unsigned short)(p0 & 0xffff);
          *(unsigned short*)(kb+16) = (unsigned short)(p1 & 0xffff);
        }
      }
    }
  }
}

// ---------------- single-pass attention + gated skip + ELU ----------------
// Q,R bf16 in QR[N][384]; K,V fp8 in KV[N][384]
// 1 wave = 1 node; 4 edges in flight, 16 lanes per edge; 1-deep KV prefetch
template<bool OUTBF>
__global__ __launch_bounds__(256) void attn_kernel(
  const unsigned short* __restrict__ QR,
  const unsigned char* __restrict__ KV,
  const int* __restrict__ row_ptr, const int* __restrict__ csr_src,
  const float* __restrict__ Wb, float* __restrict__ HoutF,
  unsigned short* __restrict__ HoutB, int N)
{
  const int wave = threadIdx.x>>6;
  const int lane = threadIdx.x&63;
  const int g    = lane>>4;          // edge slot 0..3
  const int l    = lane&15;          // channel quad 0..15
  const int n = blockIdx.x*4 + wave;
  if(n>=N) return;

  const unsigned short* nr = QR + (size_t)n*384 + 4*l;
  float4 q0 = bf4_to_f4(*(const uint2*)(nr));
  float4 q1 = bf4_to_f4(*(const uint2*)(nr+64));
  float4 q2 = bf4_to_f4(*(const uint2*)(nr+128));

  const int s0 = row_ptr[n];
  const int deg = row_ptr[n+1]-s0;

  float4 a0={0,0,0,0}, a1={0,0,0,0}, a2={0,0,0,0};
  float d0=0.f,d1=0.f,d2=0.f;

  unsigned int ku0=0,ku1=0,ku2=0,vu0=0,vu1=0,vu2=0;
  if(deg>0){
    int i0 = s0 + (g<deg ? g : 0); if(i0 > NEDGES-1) i0 = NEDGES-1;
    int sCur = csr_src[i0];
    const unsigned int* kv = (const unsigned int*)(KV + (size_t)sCur*384) + l;
    ku0=kv[0]; ku1=kv[16]; ku2=kv[32]; vu0=kv[48]; vu1=kv[64]; vu2=kv[80];
  }
  for(int base=0; base<deg; base+=4){
    // prefetch next edge-quad's K/V dwords before current compute
    const int inext = base + 4 + g;
    const int sNxt = csr_src[s0 + (inext<deg ? inext : 0)];
    const unsigned int* kvN = (const unsigned int*)(KV + (size_t)sNxt*384) + l;
    unsigned int nk0=kvN[0], nk1=kvN[16], nk2=kvN[32];
    unsigned int nv0=kvN[48], nv1=kvN[64], nv2=kvN[80];

    const bool valid = (base + g < deg);
    float4 k0 = fp8x4_to_f4(ku0);
    float4 k1 = fp8x4_to_f4(ku1);
    float4 k2 = fp8x4_to_f4(ku2);
    float p0 = q0.x*k0.x+q0.y*k0.y+q0.z*k0.z+q0.w*k0.w;
    float p1 = q1.x*k1.x+q1.y*k1.y+q1.z*k1.z+q1.w*k1.w;
    float p2 = q2.x*k2.x+q2.y*k2.y+q2.z*k2.z+q2.w*k2.w;
#pragma unroll
    for(int off=1; off<16; off<<=1){
      p0 += __shfl_xor(p0, off, 64);
      p1 += __shfl_xor(p1, off, 64);
      p2 += __shfl_xor(p2, off, 64);
    }
    float e0 = valid ? __expf(0.125f*p0) : 0.f;
    float e1 = valid ? __expf(0.125f*p1) : 0.f;
    float e2 = valid ? __expf(0.125f*p2) : 0.f;
    d0 += e0; d1 += e1; d2 += e2;
    float4 v0 = fp8x4_to_f4(vu0);
    float4 v1 = fp8x4_to_f4(vu1);
    float4 v2 = fp8x4_to_f4(vu2);
    a0.x+=e0*v0.x; a0.y+=e0*v0.y; a0.z+=e0*v0.z; a0.w+=e0*v0.w;
    a1.x+=e1*v1.x; a1.y+=e1*v1.y; a1.z+=e1*v1.z; a1.w+=e1*v1.w;
    a2.x+=e2*v2.x; a2.y+=e2*v2.y; a2.z+=e2*v2.z; a2.w+=e2*v2.w;

    ku0=nk0; ku1=nk1; ku2=nk2; vu0=nv0; vu1=nv1; vu2=nv2;
  }

  // cross-group reduction (groups hold disjoint edge subsets)
#pragma unroll
  for(int off=16; off<64; off<<=1){
    a0.x+=__shfl_xor(a0.x,off,64); a0.y+=__shfl_xor(a0.y,off,64);
    a0.z+=__shfl_xor(a0.z,off,64); a0.w+=__shfl_xor(a0.w,off,64);
    a1.x+=__shfl_xor(a1.x,off,64); a1.y+=__shfl_xor(a1.y,off,64);
    a1.z+=__shfl_xor(a1.z,off,64); a1.w+=__shfl_xor(a1.w,off,64);
    a2.x+=__shfl_xor(a2.x,off,64); a2.y+=__shfl_xor(a2.y,off,64);
    a2.z+=__shfl_xor(a2.z,off,64); a2.w+=__shfl_xor(a2.w,off,64);
    d0+=__shfl_xor(d0,off,64); d1+=__shfl_xor(d1,off,64); d2+=__shfl_xor(d2,off,64);
  }
  const float id0=1.f/(d0+1e-16f), id1=1.f/(d1+1e-16f), id2=1.f/(d2+1e-16f);
  float4 o0, o1, o2;
  o0.x=a0.x*id0; o0.y=a0.y*id0; o0.z=a0.z*id0; o0.w=a0.w*id0;
  o1.x=a1.x*id1; o1.y=a1.y*id1; o1.z=a1.z*id1; o1.w=a1.w*id1;
  o2.x=a2.x*id2; o2.y=a2.y*id2; o2.z=a2.z*id2; o2.w=a2.w*id2;

  float4 r0 = bf4_to_f4(*(const uint2*)(nr+192));
  float4 r1 = bf4_to_f4(*(const uint2*)(nr+256));
  float4 r2 = bf4_to_f4(*(const uint2*)(nr+320));

  const float* wb = Wb + 4*l;
  float4 w00=*(const float4*)(wb),     w01=*(const float4*)(wb+64),  w02=*(const float4*)(wb+128);
  float4 w10=*(const float4*)(wb+192), w11=*(const float4*)(wb+256), w12=*(const float4*)(wb+320);
  float4 w20=*(const float4*)(wb+384), w21=*(const float4*)(wb+448), w22=*(const float4*)(wb+512);
  float z =
    o0.x*w00.x+o0.y*w00.y+o0.z*w00.z+o0.w*w00.w +
    o1.x*w01.x+o1.y*w01.y+o1.z*w01.z+o1.w*w01.w +
    o2.x*w02.x+o2.y*w02.y+o2.z*w02.z+o2.w*w02.w +
    r0.x*w10.x+r0.y*w10.y+r0.z*w10.z+r0.w*w10.w +
    r1.x*w11.x+r1.y*w11.y+r1.z*w11.z+r1.w*w11.w +
    r2.x*w12.x+r2.y*w12.y+r2.z*w12.z+r2.w*w12.w +
    (o0.x-r0.x)*w20.x+(o0.y-r0.y)*w20.y+(o0.z-r0.z)*w20.z+(o0.w-r0.w)*w20.w +
    (o1.x-r1.x)*w21.x+(o1.y-r1.y)*w21.y+(o1.z-r1.z)*w21.z+(o1.w-r1.w)*w21.w +
    (o2.x-r2.x)*w22.x+(o2.y-r2.y)*w22.y+(o2.z-r2.z)*w22.z+(o2.w-r2.w)*w22.w;
#pragma unroll
  for(int off=1; off<16; off<<=1) z += __shfl_xor(z, off, 64);
  const float beta = 1.f/(1.f+__expf(-z));
  float4 h0,h1,h2;
  h0.x=beta*r0.x+(1.f-beta)*o0.x; h0.y=beta*r0.y+(1.f-beta)*o0.y;
  h0.z=beta*r0.z+(1.f-beta)*o0.z; h0.w=beta*r0.w+(1.f-beta)*o0.w;
  h1.x=beta*r1.x+(1.f-beta)*o1.x; h1.y=beta*r1.y+(1.f-beta)*o1.y;
  h1.z=beta*r1.z+(1.f-beta)*o1.z; h1.w=beta*r1.w+(1.f-beta)*o1.w;
  h2.x=beta*r2.x+(1.f-beta)*o2.x; h2.y=beta*r2.y+(1.f-beta)*o2.y;
  h2.z=beta*r2.z+(1.f-beta)*o2.z; h2.w=beta*r2.w+(1.f-beta)*o2.w;
  h0.x=(h0.x>0.f)?h0.x:expm1f(h0.x); h0.y=(h0.y>0.f)?h0.y:expm1f(h0.y);
  h0.z=(h0.z>0.f)?h0.z:expm1f(h0.z); h0.w=(h0.w>0.f)?h0.w:expm1f(h0.w);
  h1.x=(h1.x>0.f)?h1.x:expm1f(h1.x); h1.y=(h1.y>0.f)?h1.y:expm1f(h1.y);
  h1.z=(h1.z>0.f)?h1.z:expm1f(h1.z); h1.w=(h1.w>0.f)?h1.w:expm1f(h1.w);
  h2.x=(h2.x>0.f)?h2.x:expm1f(h2.x); h2.y=(h2.y>0.f)?h2.y:expm1f(h2.y);
  h2.z=(h2.z>0.f)?h2.z:expm1f(h2.z); h2.w=(h2.w>0.f)?h2.w:expm1f(h2.w);
  if(g==0){
    if(OUTBF){
      unsigned short* hb = HoutB + (size_t)n*HCDIM + 4*l;
      ushort4 u0, u1, u2;
      u0.x=f2bf(h0.x); u0.y=f2bf(h0.y); u0.z=f2bf(h0.z); u0.w=f2bf(h0.w);
      u1.x=f2bf(h1.x); u1.y=f2bf(h1.y); u1.z=f2bf(h1.z); u1.w=f2bf(h1.w);
      u2.x=f2bf(h2.x); u2.y=f2bf(h2.y); u2.z=f2bf(h2.z); u2.w=f2bf(h2.w);
      *(ushort4*)(hb)     = u0;
      *(ushort4*)(hb+64)  = u1;
      *(ushort4*)(hb+128) = u2;
    } else {
      float* ho = HoutF + (size_t)n*HCDIM + 4*l;
      *(float4*)(ho)     = h0;
      *(float4*)(ho+64)  = h1;
      *(float4*)(ho+128) = h2;
    }
  }
}

// ---------------- pooling + logits ----------------
__global__ void zero_pool(float* pooled, int* cnt){
  int i = blockIdx.x*256 + threadIdx.x;
  if(i < NGRAPH*HCDIM) ((int*)pooled)[i]=0;
  if(i < NGRAPH) cnt[i]=0;
}

// fused segment-sum + count (batch is sorted; ~2 runs per block)
__global__ void pool_k(const float* __restrict__ H, const int* __restrict__ batch,
                       float* __restrict__ pooled, int* __restrict__ cnt, int N){
  const int t = threadIdx.x;       // 192 threads = channel
  int start = blockIdx.x*256;
  int end = min(start+256, N);
  if(start>=N) return;
  int cur = batch[start];
  float acc = 0.f;
  int run = 0;
  for(int nn=start; nn<end; ++nn){
    int g = batch[nn];
    if(g!=cur){
      atomicAdd(&pooled[(size_t)cur*HCDIM+t], acc);
      if(t==0) atomicAdd(&cnt[cur], run);
      acc=0.f; run=0; cur=g;
    }
    acc += H[(size_t)nn*HCDIM+t];
    run++;
  }
  atomicAdd(&pooled[(size_t)cur*HCDIM+t], acc);
  if(t==0) atomicAdd(&cnt[cur], run);
}

__global__ void logits_k(const float* __restrict__ pooled, const int* __restrict__ cnt,
                         const float* __restrict__ Wlin, const float* __restrict__ blin,
                         float* __restrict__ out){
  const int g = blockIdx.x;
  const int lane = threadIdx.x;    // 64 threads
  float c = fmaxf((float)cnt[g], 1.f);
  float s = 0.f;
#pragma unroll
  for(int j=0;j<3;++j){
    int col = j*64+lane;
    s += pooled[(size_t)g*HCDIM+col]/c * Wlin[col];
  }
  s = wave_sum(s);
  if(lane==0) out[g] = s + blin[0];
}

extern "C" void kernel_launch(void* const* d_in, const int* in_sizes, int n_in,
                              void* d_out, int out_size, void* d_ws, size_t ws_size,
                              hipStream_t stream)
{
  const int N=NNODES, E=NEDGES;
  const float* x     = (const float*)d_in[0];
  const int*   ei    = (const int*)d_in[1];
  const int*   batch = (const int*)d_in[2];
  const int* esrc = ei;
  const int* edst = ei + E;
  const float* Wq0=(const float*)d_in[3];  const float* bq0=(const float*)d_in[4];
  const float* Wk0=(const float*)d_in[5];  const float* bk0=(const float*)d_in[6];
  const float* Wv0=(const float*)d_in[7];  const float* bv0=(const float*)d_in[8];
  const float* Ws0=(const float*)d_in[9];  const float* bs0=(const float*)d_in[10];
  const float* Wb0=(const float*)d_in[11];
  const float* Wq1=(const float*)d_in[12]; const float* bq1=(const float*)d_in[13];
  const float* Wk1=(const float*)d_in[14]; const float* bk1=(const float*)d_in[15];
  const float* Wv1=(const float*)d_in[16]; const float* bv1=(const float*)d_in[17];
  const float* Ws1=(const float*)d_in[18]; const float* bs1=(const float*)d_in[19];
  const float* Wb1=(const float*)d_in[20];
  const float* Wlin=(const float*)d_in[21];
  const float* blin=(const float*)d_in[22];
  float* out = (float*)d_out;

  char* p = (char*)d_ws;
  auto alloc = [&](size_t bytes)->char*{
    char* q = p; p += (bytes+255)/256*256; return q;
  };
  unsigned short* Xb   = (unsigned short*)alloc((size_t)N*HCDIM*2);
  unsigned short* QR   = (unsigned short*)alloc((size_t)N*384*2);
  unsigned char*  KV   = (unsigned char*)alloc((size_t)N*384);
  float* H1            = (float*)alloc((size_t)N*HCDIM*4);
  unsigned short* Wt   = (unsigned short*)alloc((size_t)QKVRW*HCDIM*2);
  float* bcat          = (float*)alloc(QKVRW*4);
  int* counts  = (int*)alloc((size_t)N*4);
  int* cursor  = (int*)alloc((size_t)N*4);
  int* row_ptr = (int*)alloc((size_t)(N+1)*4);
  int* csr     = (int*)alloc((size_t)E*4);
  int* bsum    = (int*)alloc(4096);
  float* pooled= (float*)alloc((size_t)NGRAPH*HCDIM*4);
  int* cnt     = (int*)alloc(256);

  const int NB = (N+255)/256;

  // ---- CSR build ----
  zero2_k<<<(N+255)/256,256,0,stream>>>(counts,cursor,N);
  hist_k<<<(E+255)/256,256,0,stream>>>(edst,counts,E);
  scan_partial<<<NB,256,0,stream>>>(counts,bsum,N);
  scan_bsum<<<1,1024,0,stream>>>(bsum,NB);
  scan_final<<<NB,256,0,stream>>>(counts,bsum,row_ptr,N);
  fill_k<<<(E+255)/256,256,0,stream>>>(esrc,edst,row_ptr,cursor,csr,E);

  dim3 ggemm((N+127)/128, 12);
  // ---- layer 0 ----
  prep0_k<<<CAST_BLKS + (QKVRW*DIM_IN+255)/256, 256, 0, stream>>>(
      x, Xb, Wq0,Wk0,Wv0,Ws0, bq0,bk0,bv0,bs0, Wt, bcat);
  gemm_mfma<DIM_IN><<<ggemm,256,0,stream>>>(Xb,Wt,bcat,QR,KV,N);
  attn_kernel<true><<<(N+3)/4,256,0,stream>>>(QR,KV,row_ptr,csr,Wb0,nullptr,Xb,N);
  // ---- layer 1 ----
  build_wt<<<(QKVRW*HCDIM+255)/256,256,0,stream>>>(Wq1,Wk1,Wv1,Ws1,bq1,bk1,bv1,bs1,Wt,bcat,HCDIM);
  gemm_mfma<HCDIM><<<ggemm,256,0,stream>>>(Xb,Wt,bcat,QR,KV,N);
  attn_kernel<false><<<(N+3)/4,256,0,stream>>>(QR,KV,row_ptr,csr,Wb1,H1,nullptr,N);

  // ---- pooling + logits ----
  zero_pool<<<(NGRAPH*HCDIM+255)/256,256,0,stream>>>(pooled,cnt);
  pool_k<<<(N+255)/256,192,0,stream>>>(H1,batch,pooled,cnt,N);
  logits_k<<<NGRAPH,64,0,stream>>>(pooled,cnt,Wlin,blin,out);
}